// Round 21
// baseline (54.836 us; speedup 1.0000x reference)
//
#include <hip/hip_runtime.h>

#define HID 768
#define NL  17
#define BB  64
#define TT  512

#define SEG  16
#define SLEN 32
#define QST  352

typedef __attribute__((ext_vector_type(8))) short bf16x8;
typedef __attribute__((ext_vector_type(4))) float f32x4;

// v_cvt_pk_bf16_f32: dst.lo16 = bf16(a) RNE, dst.hi16 = bf16(b)
__device__ __forceinline__ unsigned cvtpk(float a, float b) {
    unsigned r;
    asm("v_cvt_pk_bf16_f32 %0, %1, %2" : "=v"(r) : "v"(a), "v"(b));
    return r;
}

// ===========================================================================
// Kernel 1 (FUSED): emissions GEMM + CRF segment scan. R19 structure with
// ONE new lever: x loads are NON-TEMPORAL (nt) — x streams 96MB used-once
// through L1(32K)/L2(4M) with 100% allocate-evict thrash; nt skips
// allocation. (R20 fix: nontemporal builtin needs clang ext_vector_type,
// not HIP_vector_type — use f32x4.)
// Block 0's tid 255 also zeroes the loss slot for the fused-atomic combine.
// ===========================================================================
__global__ __launch_bounds__(256) void emis_scan_kernel(const float* __restrict__ x,
                                                        const float* __restrict__ w,
                                                        const float* __restrict__ bias,
                                                        const int* __restrict__ mask,
                                                        const float* __restrict__ tr_,
                                                        float* __restrict__ y,
                                                        float* __restrict__ ws,
                                                        float* __restrict__ loss) {
    __shared__ unsigned short WP[2][18][776];   // 55.9 KB palette
    __shared__ float em_s[64][20];              // 5.1 KB  this block's emissions
    __shared__ float QT[2][2][18][20];          // 5.8 KB  per-segment scan state

    const int tid = threadIdx.x;

    if (blockIdx.x == 0 && tid == 255) *loss = 0.f;   // for combine's atomics

    // ---- stage w as bf16 hi/lo palette (once per block) ----
    for (int e = tid; e < 776; e += 256) { WP[0][17][e] = 0; WP[1][17][e] = 0; }
#pragma unroll
    for (int j = 0; j < 13; ++j) {
        const int g4 = tid + 256 * j;           // float4 granule 0..3263
        if (g4 < 3264) {
            const f32x4 f = *reinterpret_cast<const f32x4*>(w + 4 * g4);
            const int col = g4 / 192;
            const int e   = (g4 - col * 192) * 4;
            const unsigned h0 = cvtpk(f.x, f.y);
            const unsigned h1 = cvtpk(f.z, f.w);
            const unsigned l0 = cvtpk(f.x - __uint_as_float(h0 << 16),
                                      f.y - __uint_as_float(h0 & 0xFFFF0000u));
            const unsigned l1 = cvtpk(f.z - __uint_as_float(h1 << 16),
                                      f.w - __uint_as_float(h1 & 0xFFFF0000u));
            uint2 hv; hv.x = h0; hv.y = h1;
            uint2 lv; lv.x = l0; lv.y = l1;
            *reinterpret_cast<uint2*>(&WP[0][col][e]) = hv;
            *reinterpret_cast<uint2*>(&WP[1][col][e]) = lv;
        }
    }
    __syncthreads();

    const int lane = tid & 63;
    const int c0   = lane & 15;                 // A row / B col / D col
    int c1 = 16 + c0; if (c1 > 17) c1 = 17;     // n-tile 1 col (>=17 -> zeros)
    const int kg   = (lane >> 4) * 8;
    const int mloc = tid >> 6;                  // local mtile 0..3
    const int mtile = blockIdx.x * 4 + mloc;
    const float* xp = x + (size_t)(mtile * 16 + c0) * HID + kg;

    const unsigned short* pH0 = &WP[0][c0][kg];
    const unsigned short* pH1 = &WP[0][c1][kg];
    const unsigned short* pL0 = &WP[1][c0][kg];
    const unsigned short* pL1 = &WP[1][c1][kg];

    f32x4 acc0 = {0.f, 0.f, 0.f, 0.f};
    f32x4 acc1 = {0.f, 0.f, 0.f, 0.f};

    // non-temporal x loads: skip L1/L2 allocation (streaming, used once)
#define LDX(T)  __builtin_nontemporal_load(reinterpret_cast<const f32x4*>(xp + 32 * (T)))
#define LDX4(T) __builtin_nontemporal_load(reinterpret_cast<const f32x4*>(xp + 32 * (T) + 4))

#define XSTEP(Q0, Q1, T)                                                      \
    {                                                                         \
        const int LK = 32 * (T);                                              \
        union { unsigned u[4]; bf16x8 v; } H_, L_;                            \
        H_.u[0] = cvtpk(Q0.x, Q0.y);                                          \
        H_.u[1] = cvtpk(Q0.z, Q0.w);                                          \
        H_.u[2] = cvtpk(Q1.x, Q1.y);                                          \
        H_.u[3] = cvtpk(Q1.z, Q1.w);                                          \
        L_.u[0] = cvtpk(Q0.x - __uint_as_float(H_.u[0] << 16),                \
                        Q0.y - __uint_as_float(H_.u[0] & 0xFFFF0000u));       \
        L_.u[1] = cvtpk(Q0.z - __uint_as_float(H_.u[1] << 16),                \
                        Q0.w - __uint_as_float(H_.u[1] & 0xFFFF0000u));       \
        L_.u[2] = cvtpk(Q1.x - __uint_as_float(H_.u[2] << 16),                \
                        Q1.y - __uint_as_float(H_.u[2] & 0xFFFF0000u));       \
        L_.u[3] = cvtpk(Q1.z - __uint_as_float(H_.u[3] << 16),                \
                        Q1.w - __uint_as_float(H_.u[3] & 0xFFFF0000u));       \
        const bf16x8 bh0 = *reinterpret_cast<const bf16x8*>(pH0 + LK);        \
        const bf16x8 bh1 = *reinterpret_cast<const bf16x8*>(pH1 + LK);        \
        const bf16x8 bl0 = *reinterpret_cast<const bf16x8*>(pL0 + LK);        \
        const bf16x8 bl1 = *reinterpret_cast<const bf16x8*>(pL1 + LK);        \
        acc0 = __builtin_amdgcn_mfma_f32_16x16x32_bf16(H_.v, bh0, acc0, 0, 0, 0); \
        acc0 = __builtin_amdgcn_mfma_f32_16x16x32_bf16(H_.v, bl0, acc0, 0, 0, 0); \
        acc0 = __builtin_amdgcn_mfma_f32_16x16x32_bf16(L_.v, bh0, acc0, 0, 0, 0); \
        acc1 = __builtin_amdgcn_mfma_f32_16x16x32_bf16(H_.v, bh1, acc1, 0, 0, 0); \
        acc1 = __builtin_amdgcn_mfma_f32_16x16x32_bf16(H_.v, bl1, acc1, 0, 0, 0); \
        acc1 = __builtin_amdgcn_mfma_f32_16x16x32_bf16(L_.v, bh1, acc1, 0, 0, 0); \
    }

    // 4-deep rotation: qA..qD named pairs, 6KB/wave in flight at every stall
    f32x4 qA0 = LDX(0), qA1 = LDX4(0);
    f32x4 qB0 = LDX(1), qB1 = LDX4(1);
    f32x4 qC0 = LDX(2), qC1 = LDX4(2);
    f32x4 qD0 = LDX(3), qD1 = LDX4(3);

#pragma unroll
    for (int t = 0; t < 24; t += 4) {
        XSTEP(qA0, qA1, t)
        if (t + 4 < 24) { qA0 = LDX(t + 4); qA1 = LDX4(t + 4); }
        XSTEP(qB0, qB1, t + 1)
        if (t + 5 < 24) { qB0 = LDX(t + 5); qB1 = LDX4(t + 5); }
        XSTEP(qC0, qC1, t + 2)
        if (t + 6 < 24) { qC0 = LDX(t + 6); qC1 = LDX4(t + 6); }
        XSTEP(qD0, qD1, t + 3)
        if (t + 7 < 24) { qD0 = LDX(t + 7); qD1 = LDX4(t + 7); }
    }
#undef XSTEP
#undef LDX
#undef LDX4

    // ---- epilogue: global write + LDS scatter for the in-block scan ----
    const float bc  = bias[c0];
    const float b16 = bias[16];
    const int   rb  = mtile * 16 + (lane >> 4) * 4;
    const int   lr  = mloc * 16 + (lane >> 4) * 4;     // local row base
#pragma unroll
    for (int i = 0; i < 4; ++i) {
        const int row = rb + i;
        const float v0 = acc0[i] + bc;
        y[(size_t)row * NL + c0] = v0;
        em_s[lr + i][c0] = v0;
        if (c0 == 0) {
            const float v1 = acc1[i] + b16;
            y[(size_t)row * NL + 16] = v1;
            em_s[lr + i][16] = v1;
        }
    }
    __syncthreads();                            // em_s complete

    // ---- scan phase: waves 0,1 each run one 32-step segment ----
    const int widx = tid >> 6;
    if (widx >= 2) return;
    {
        const int l  = lane;
        const int b  = blockIdx.x >> 3;          // batch
        const int q8 = blockIdx.x & 7;
        const int sl = (q8 << 1) + widx;         // segment 0..15
        const int T0 = q8 << 6;                  // batch-step of local row 0

        int lenp = 0;
#pragma unroll
        for (int m = 0; m < 8; ++m) lenp += (mask[b * TT + l + 64 * m] != 0);
#pragma unroll
        for (int off = 32; off; off >>= 1) lenp += __shfl_down(lenp, off);
        const int len = __shfl(lenp, 0);

        const int tstart = (32 * sl > 1) ? 32 * sl : 1;
        int tend = 32 * sl + 32; if (tend > len) tend = len;
        const int trips = tend - tstart;

        const bool act = (l < 51);
        const int  i   = act ? (l / 3) : 0;
        const int  m3  = act ? (l - 3 * (l / 3)) : 0;
        const int  j0  = 6 * m3;

        if (act) {
#pragma unroll
            for (int jj = 0; jj < 6; ++jj)
                QT[widx][0][j0 + jj][i] = (i == j0 + jj) ? 1.f : 0.f;
        }

        float at[17];
#pragma unroll
        for (int k = 0; k < 17; ++k) at[k] = __expf(tr_[k * NL + i]);

        float psc = 1.f;
        int   Mi  = 0;
        float emv = (trips > 0) ? em_s[tstart - T0][i] : 0.f;
        int   t   = tstart;

#define QSTEPF(SRC, DST, TCUR)                                                \
    {                                                                         \
        const float e_ = __expf(emv) * psc;  psc = 1.f;                       \
        int ln_ = (TCUR) + 1 - T0; ln_ = (ln_ < 63) ? ln_ : 63;               \
        const float env_ = em_s[ln_][i];                                      \
        float o[6];                                                           \
        _Pragma("unroll")                                                     \
        for (int jj = 0; jj < 6; ++jj) {                                      \
            const float* qr = &QT[widx][SRC][j0 + jj][0];                     \
            const float4 a0 = *reinterpret_cast<const float4*>(qr);           \
            const float4 a1 = *reinterpret_cast<const float4*>(qr + 4);       \
            const float4 a2 = *reinterpret_cast<const float4*>(qr + 8);       \
            const float4 a3 = *reinterpret_cast<const float4*>(qr + 12);      \
            const float aL  = qr[16];                                         \
            float u0 = at[0] * a0.x, u1 = at[1] * a0.y;                       \
            float u2 = at[2] * a0.z, u3 = at[3] * a0.w;                       \
            u0 = fmaf(at[4],  a1.x, u0); u1 = fmaf(at[5],  a1.y, u1);         \
            u2 = fmaf(at[6],  a1.z, u2); u3 = fmaf(at[7],  a1.w, u3);         \
            u0 = fmaf(at[8],  a2.x, u0); u1 = fmaf(at[9],  a2.y, u1);         \
            u2 = fmaf(at[10], a2.z, u2); u3 = fmaf(at[11], a2.w, u3);         \
            u0 = fmaf(at[12], a3.x, u0); u1 = fmaf(at[13], a3.y, u1);         \
            u2 = fmaf(at[14], a3.z, u2); u3 = fmaf(at[15], a3.w, u3);         \
            u0 = fmaf(at[16], aL,   u0);                                      \
            o[jj] = (u0 + u1) + (u2 + u3);                                    \
        }                                                                     \
        if (act) {                                                            \
            _Pragma("unroll")                                                 \
            for (int jj = 0; jj < 6; ++jj)                                    \
                QT[widx][DST][j0 + jj][i] = e_ * o[jj];                       \
        }                                                                     \
        emv = env_;                                                           \
    }

        for (int pp = 0; pp < (trips >> 1); ++pp) {
            QSTEPF(0, 1, t)
            QSTEPF(1, 0, t + 1)
            t += 2;
            const float q00 = QT[widx][0][0][0];
            const int E = (int)((__float_as_uint(q00) >> 23) & 0xff) - 127;
            Mi += E;
            psc = __builtin_amdgcn_ldexpf(1.f, -E);
        }
        int sbuf = 0;
        if (trips > 0 && (trips & 1)) { QSTEPF(0, 1, t) sbuf = 1; }
#undef QSTEPF

        const int bs = b * SEG + sl;
        if (act) {
            float* dst = ws + (size_t)bs * QST + i * 20;
#pragma unroll
            for (int jj = 0; jj < 6; ++jj) {
                const int j = j0 + jj;
                if (j < 17) dst[j] = psc * QT[widx][sbuf][j][i];
            }
        }
        if (l == 0) ws[(size_t)bs * QST + 340] = (float)Mi;
    }
}

// ===========================================================================
// Kernel 2: combine + fused loss (atomicAdd of -llh/BB; loss zeroed by k1).
// ===========================================================================
__device__ __forceinline__ float bcast(float v, int i) {
    return __uint_as_float(__builtin_amdgcn_readlane(__float_as_uint(v), i));
}

__global__ __launch_bounds__(64) void crf_combine_kernel(const float* __restrict__ emis,
                                                         const float* __restrict__ st_,
                                                         const float* __restrict__ en_,
                                                         const float* __restrict__ tr_,
                                                         const int* __restrict__ labels,
                                                         const int* __restrict__ mask,
                                                         const float* __restrict__ ws,
                                                         float* __restrict__ loss) {
    const int b = blockIdx.x;
    const int l = threadIdx.x;
    const float* eb = emis + (size_t)b * TT * NL;
    const int*   lb = labels + b * TT;

    int lenp = 0;
#pragma unroll
    for (int m = 0; m < 8; ++m) lenp += (mask[b * TT + l + 64 * m] != 0);
#pragma unroll
    for (int off = 32; off; off >>= 1) lenp += __shfl_down(lenp, off);
    const int len = __shfl(lenp, 0);

    float np = 0.f;
#pragma unroll
    for (int m = 0; m < 8; ++m) {
        const int t = l + 64 * m;
        int tag = lb[t]; if ((unsigned)tag >= NL) tag = 0;
        if (t < len) {
            if (t == 0) {
                np += st_[tag] + eb[tag];
            } else {
                int tp = lb[t - 1]; if ((unsigned)tp >= NL) tp = 0;
                np += tr_[tp * NL + tag] + eb[t * NL + tag];
            }
            if (t == len - 1) np += en_[tag];
        }
    }
#pragma unroll
    for (int off = 32; off; off >>= 1) np += __shfl_down(np, off);
    const float num = __shfl(np, 0);

    const bool act = (l < NL);
    const int  j   = act ? l : 0;

    float p  = act ? __expf(st_[j] + eb[j]) : 0.f;
    int   Mi = 0;

    for (int s = 0; s < SEG; ++s) {
        const float* qs = ws + (size_t)(b * SEG + s) * QST;
        const float* qr = qs + j * 20;
        const float4 a0 = *reinterpret_cast<const float4*>(qr);
        const float4 a1 = *reinterpret_cast<const float4*>(qr + 4);
        const float4 a2 = *reinterpret_cast<const float4*>(qr + 8);
        const float4 a3 = *reinterpret_cast<const float4*>(qr + 12);
        const float  aL = qr[16];
        const float  Msc = qs[340];

        float u0 = a0.x * bcast(p, 0),  u1 = a0.y * bcast(p, 1);
        float u2 = a0.z * bcast(p, 2),  u3 = a0.w * bcast(p, 3);
        u0 = fmaf(a1.x, bcast(p, 4),  u0); u1 = fmaf(a1.y, bcast(p, 5),  u1);
        u2 = fmaf(a1.z, bcast(p, 6),  u2); u3 = fmaf(a1.w, bcast(p, 7),  u3);
        u0 = fmaf(a2.x, bcast(p, 8),  u0); u1 = fmaf(a2.y, bcast(p, 9),  u1);
        u2 = fmaf(a2.z, bcast(p, 10), u2); u3 = fmaf(a2.w, bcast(p, 11), u3);
        u0 = fmaf(a3.x, bcast(p, 12), u0); u1 = fmaf(a3.y, bcast(p, 13), u1);
        u2 = fmaf(a3.z, bcast(p, 14), u2); u3 = fmaf(a3.w, bcast(p, 15), u3);
        u0 = fmaf(aL,   bcast(p, 16), u0);
        p = act ? ((u0 + u1) + (u2 + u3)) : 0.f;
        Mi += (int)Msc;

        const unsigned pb = (unsigned)__builtin_amdgcn_readlane((int)__float_as_uint(p), 0);
        const int e = (int)((pb >> 23) & 0xff) - 127;
        Mi += e;
        p = __builtin_amdgcn_ldexpf(p, -e);
    }

    float v = act ? p * __expf(en_[j]) : 0.f;
#pragma unroll
    for (int off = 32; off; off >>= 1) v += __shfl_down(v, off);

    if (l == 0) {
        const float denom = (float)Mi * 0.6931471805599453f + __logf(v);
        atomicAdd(loss, -(num - denom) * (1.0f / BB));
    }
}

// ===========================================================================
extern "C" void kernel_launch(void* const* d_in, const int* in_sizes, int n_in,
                              void* d_out, int out_size, void* d_ws, size_t ws_size,
                              hipStream_t stream) {
    const float* outputs = (const float*)d_in[0];
    const float* fc_w    = (const float*)d_in[1];
    const float* fc_b    = (const float*)d_in[2];
    const float* start_t = (const float*)d_in[3];
    const float* end_t   = (const float*)d_in[4];
    const float* trans   = (const float*)d_in[5];
    const int*   labels  = (const int*)d_in[6];
    const int*   mask    = (const int*)d_in[7];

    float* emis = (float*)d_out;
    float* loss = emis + (size_t)BB * TT * NL;
    float* ws   = (float*)d_ws;

    emis_scan_kernel<<<(BB * TT) / 64, 256, 0, stream>>>(outputs, fc_w, fc_b,
                                                         mask, trans, emis, ws, loss);
    crf_combine_kernel<<<BB, 64, 0, stream>>>(emis, start_t, end_t, trans,
                                              labels, mask, ws, loss);
}